// Round 2
// baseline (174.535 us; speedup 1.0000x reference)
//
#include <hip/hip_runtime.h>
#include <math.h>

// Whiten: per-(b,c) mean/std normalization over 224x224 fp32 slices.
// B*C = 2048 slices of 50176 floats. Memory-bound: floor = 822 MB @ 6.3 TB/s
// ~= 131 us.
//
// R2 structure: persistent pipeline. 256 blocks (1 per CU), 1024 threads,
// 8 slices per block, TWO register slice-buffers (va/vb). While slice s is
// reduced/normalized/stored from one buffer, the 13 float4 loads of slice
// s+1 fill the other. The stats barrier is a raw s_barrier preceded only by
// s_waitcnt lgkmcnt(0) -- __syncthreads() would drain vmcnt(0) and kill the
// prefetch. LDS stat arrays are double-buffered so one barrier per slice is
// race-free (reader of wred[b] passes the NEXT barrier before wred[b] is
// rewritten two slices later).

namespace {
constexpr int kHW       = 224 * 224;                  // 50176
constexpr int kHW4      = kHW / 4;                    // 12544 float4 / slice
constexpr int kThreads  = 1024;
constexpr int kIt       = kHW4 / kThreads;            // 12 full float4 / thread
constexpr int kExtra    = kHW4 - kIt * kThreads;      // 256 tail float4
constexpr int kSlices   = 64 * 32;                    // 2048
constexpr int kPerBlock = 8;
constexpr int kBlocks   = kSlices / kPerBlock;        // 256
constexpr int kWaves    = kThreads / 64;              // 16
constexpr float kMinDev = 1.0f / 224.0f;              // 1/sqrt(H*W)
}

__global__ __launch_bounds__(kThreads, 4)
void whiten_pipe(const float* __restrict__ x, float* __restrict__ y) {
    __shared__ float2 wred[2][kWaves];   // double-buffered per-wave (sum, sumsq)

    const int  tid   = threadIdx.x;
    const int  wid   = tid >> 6;
    const int  lane  = tid & 63;
    const bool extra = (tid < kExtra);
    const size_t base = (size_t)blockIdx.x * kPerBlock * kHW4;
    const float4* __restrict__ xs = reinterpret_cast<const float4*>(x) + base;
    float4* __restrict__ ys       = reinterpret_cast<float4*>(y) + base;

    float4 va[kIt + 1], vb[kIt + 1];

    auto load = [&](float4 (&v)[kIt + 1], int s) {
        const float4* __restrict__ p = xs + (size_t)s * kHW4;
#pragma unroll
        for (int i = 0; i < kIt; ++i) v[i] = p[tid + i * kThreads];
        if (extra) v[kIt] = p[kIt * kThreads + tid];
        else       v[kIt] = make_float4(0.f, 0.f, 0.f, 0.f);
    };

    auto process = [&](float4 (&v)[kIt + 1], int s, int buf) {
        // per-thread partials (tail lane contributes zeros when !extra)
        float sum = 0.f, ssq = 0.f;
#pragma unroll
        for (int i = 0; i < kIt + 1; ++i) {
            sum += v[i].x + v[i].y + v[i].z + v[i].w;
            ssq = fmaf(v[i].x, v[i].x, ssq);
            ssq = fmaf(v[i].y, v[i].y, ssq);
            ssq = fmaf(v[i].z, v[i].z, ssq);
            ssq = fmaf(v[i].w, v[i].w, ssq);
        }
        // wave64 butterfly
#pragma unroll
        for (int off = 32; off >= 1; off >>= 1) {
            sum += __shfl_down(sum, off, 64);
            ssq += __shfl_down(ssq, off, 64);
        }
        if (lane == 0) wred[buf][wid] = make_float2(sum, ssq);
        // LDS-only barrier: do NOT drain vmcnt (prefetch of next slice is in
        // flight). "memory" clobber orders the LDS accesses around it.
        asm volatile("s_waitcnt lgkmcnt(0)\n\ts_barrier" ::: "memory");
        float S = 0.f, SS = 0.f;
#pragma unroll
        for (int i = 0; i < kWaves; ++i) {
            const float2 t = wred[buf][i];
            S += t.x; SS += t.y;
        }
        const float mean = S * (1.0f / kHW);
        float var = (SS - S * mean) * (1.0f / (kHW - 1));
        var = fmaxf(var, 0.f);
        const float rcp = 1.0f / fmaxf(sqrtf(var), kMinDev);

        float4* __restrict__ p = ys + (size_t)s * kHW4;
#pragma unroll
        for (int i = 0; i < kIt; ++i) {
            float4 o;
            o.x = (v[i].x - mean) * rcp;
            o.y = (v[i].y - mean) * rcp;
            o.z = (v[i].z - mean) * rcp;
            o.w = (v[i].w - mean) * rcp;
            p[tid + i * kThreads] = o;
        }
        if (extra) {
            float4 o;
            o.x = (v[kIt].x - mean) * rcp;
            o.y = (v[kIt].y - mean) * rcp;
            o.z = (v[kIt].z - mean) * rcp;
            o.w = (v[kIt].w - mean) * rcp;
            p[kIt * kThreads + tid] = o;
        }
    };

    load(va, 0);
#pragma unroll
    for (int s = 0; s < kPerBlock; s += 2) {
        load(vb, s + 1);                       // prefetch odd slice
        process(va, s, 0);                     // consume even slice
        if (s + 2 < kPerBlock) load(va, s + 2); // prefetch next even slice
        process(vb, s + 1, 1);                 // consume odd slice
    }
}

extern "C" void kernel_launch(void* const* d_in, const int* in_sizes, int n_in,
                              void* d_out, int out_size, void* d_ws, size_t ws_size,
                              hipStream_t stream) {
    (void)in_sizes; (void)n_in; (void)d_ws; (void)ws_size; (void)out_size;
    const float* x = reinterpret_cast<const float*>(d_in[0]);
    float* y = reinterpret_cast<float*>(d_out);
    whiten_pipe<<<kBlocks, kThreads, 0, stream>>>(x, y);
}